// Round 10
// baseline (231.354 us; speedup 1.0000x reference)
//
#include <hip/hip_runtime.h>
#include <hip/hip_bf16.h>

typedef short bf16x8 __attribute__((ext_vector_type(8)));
typedef float f32x4 __attribute__((ext_vector_type(4)));
typedef float f32x2 __attribute__((ext_vector_type(2)));

#define BCAP 8192   // per-bucket bin capacity (mean ~4096 for E=1.6M, NB=391)

// LEDGER (rounds 1-9):
// - Lane-reduce W2 fusion: 3 variants, all lose >=28us vs MFMA. Don't re-fuse that way.
// - Inline-asm pk ops destroy load hoisting (r1); plain-C f32x2 neutral (r6).
// - gather128 is L2-miss-path bound (~3.0-3.5 TB/s), NOT VALU-bound (r6) and NOT
//   scalar-L2-load bound (r9 neutral): L2-resident scalar loads pipeline for free.
// - Wave count must be >~3x the 8192 slots for dynamic refill (r4: 40%, r7: 54%).
// - r8 block 16-node tile + MFMA tail: 228.8us, conflicts 0, WRITE 25->3.1MB.
// - r10: (a) barrier-free tail — D-row m depends only on A-row m, so each wave
//   runs the MFMA itself and stores only kq==wave rows (own LDS writes, same-wave
//   ordering; garbage rows discarded). (b) binB overlapped with gemm1's 2nd half
//   (binB alone = 391 blocks, 35KB LDS, ~19% occ — was serialized).

__device__ inline float bf2f(unsigned short u) {
    union { unsigned int i; float f; } v; v.i = ((unsigned int)u) << 16; return v.f;
}
__device__ inline unsigned short f2bf(float f) {
    union { float f; unsigned int i; } v; v.f = f;
    unsigned int r = v.i + 0x7FFFu + ((v.i >> 16) & 1u);
    return (unsigned short)(r >> 16);
}
__device__ inline float u_lo(unsigned u) {
    union { unsigned i; float f; } v; v.i = u << 16; return v.f;
}
__device__ inline float u_hi(unsigned u) {
    union { unsigned i; float f; } v; v.i = u & 0xFFFF0000u; return v.f;
}
__device__ inline void acc8p(f32x2* ac, uint4 v) {
    f32x2 t;
    t.x = u_lo(v.x); t.y = u_hi(v.x); ac[0] += t;
    t.x = u_lo(v.y); t.y = u_hi(v.y); ac[1] += t;
    t.x = u_lo(v.z); t.y = u_hi(v.z); ac[2] += t;
    t.x = u_lo(v.w); t.y = u_hi(v.w); ac[3] += t;
}
__device__ inline void acc8sp(f32x2* ac, uint4 v, float d) {   // ac += d*v
    f32x2 dd; dd.x = d; dd.y = d;
    f32x2 t;
    t.x = u_lo(v.x); t.y = u_hi(v.x); ac[0] += t * dd;
    t.x = u_lo(v.y); t.y = u_hi(v.y); ac[1] += t * dd;
    t.x = u_lo(v.z); t.y = u_hi(v.z); ac[2] += t * dd;
    t.x = u_lo(v.w); t.y = u_hi(v.w); ac[3] += t * dd;
}

// ---- fused setup: fragment-table precompute + bias conversion + init + flags.
__global__ __launch_bounds__(256) void k_setup(
    const void* __restrict__ W1r, const void* __restrict__ W2r,
    const void* __restrict__ b1r, const void* __restrict__ b2r,
    const unsigned int* __restrict__ eiraw,
    unsigned short* __restrict__ Wf1, unsigned short* __restrict__ Wf2,
    float* __restrict__ bb1, float* __restrict__ bb2,
    int* __restrict__ bin_cnt, int* gctr, int* flags, int NB)
{
    __shared__ int cs, ce;
    int blk = blockIdx.x, tid = threadIdx.x;
    const unsigned short* w1u = (const unsigned short*)W1r;
    int lf = 0;
    for (int i = tid; i < 4096; i += 256) {
        unsigned e = (w1u[i] >> 7) & 0xFF;
        lf += (e >= 0x90);               // |val| >= 2^17: impossible for real bf16 weights
    }
    for (int o = 32; o; o >>= 1) lf += __shfl_down(lf, o);
    if (tid == 0) { cs = 0; ce = 0; }
    __syncthreads();
    if ((tid & 63) == 0 && lf) atomicAdd(&cs, lf);
    __syncthreads();
    bool isf32 = cs > 16;
    const float* w1f = (const float*)W1r;
    const unsigned short* w1b = (const unsigned short*)W1r;
    const float* w2f = (const float*)W2r;
    const unsigned short* w2b = (const unsigned short*)W2r;

    if (blk < 8) {                       // Wf1: 2048 fragment entries x 8 shorts
        int idx = blk * 256 + tid;
        int kc = idx >> 9, rem = idx & 511;
        int ct = rem >> 6, l = rem & 63;
        int n = ct * 16 + (l & 15);
        int kbase = kc * 32 + (l >> 4) * 8;
        unsigned short* d = &Wf1[idx * 8];
#pragma unroll
        for (int j = 0; j < 8; j++) {
            int s = (kbase + j) * 128 + n;
            d[j] = isf32 ? f2bf(w1f[s]) : w1b[s];
        }
    } else if (blk == 8) {               // Wf2: 256 entries x 8 shorts
        int idx = tid;
        int kc = idx >> 6, l = idx & 63;
        int mrow = l & 15, kq = l >> 4;
        unsigned short* d = &Wf2[idx * 8];
#pragma unroll
        for (int j = 0; j < 8; j++) {
            int s = (kc * 32 + kq * 8 + j) * 16 + mrow;
            d[j] = isf32 ? f2bf(w2f[s]) : w2b[s];
        }
    } else if (blk == 9) {
        if (tid < 128) bb1[tid] = isf32 ? ((const float*)b1r)[tid] : bf2f(((const unsigned short*)b1r)[tid]);
        else if (tid < 144) bb2[tid - 128] = isf32 ? ((const float*)b2r)[tid - 128] : bf2f(((const unsigned short*)b2r)[tid - 128]);
    } else if (blk == 10) {
        for (int i = tid; i < NB; i += 256) bin_cnt[i] = 0;
        if (tid == 0) *gctr = 0;
    } else {                             // blk == 11: flags
        int le = 0;
        for (int i = tid; i < 128; i += 256)
            if ((i & 1) && eiraw[i] != 0) le++;
        for (int o = 32; o; o >>= 1) le += __shfl_down(le, o);
        if ((tid & 63) == 0 && le) atomicAdd(&ce, le);
        __syncthreads();
        if (tid == 0) { flags[0] = isf32 ? 1 : 0; flags[1] = (ce == 0) ? 1 : 0; }
    }
}

// ---- binA body: LDS bucket-sort 4096 edges, coalesced run-writes into bin ----
__device__ __forceinline__ void binA_body(int* smem, const void* __restrict__ ei,
                                          int* __restrict__ bin_cnt, int* __restrict__ bin,
                                          int E, int NB, const int* __restrict__ flags) {
    int* cnt  = smem;                     // 512
    int* pfx  = smem + 512;               // 512
    int* cur  = smem + 1024;              // 512
    int* dl   = smem + 1536;              // 512
    int* ssum = smem + 2048;              // 256
    int* sortw = smem + 2304;             // 4096
    unsigned short* sortb = (unsigned short*)(smem + 6400);   // 4096 shorts
    int tid = threadIdx.x;
    for (int i = tid; i < 512; i += 256) cnt[i] = 0;
    bool i64 = flags[1] != 0;
    long e0 = (long)blockIdx.x * 4096;
    int total = (int)min((long)4096, (long)E - e0);
    int src[16], dst[16];
#pragma unroll
    for (int i = 0; i < 16; i++) {
        long e = e0 + i * 256 + tid;
        if (e < E) {
            if (i64) {
                src[i] = (int)((const long long*)ei)[e];
                dst[i] = (int)((const long long*)ei)[(long)E + e];
            } else {
                src[i] = ((const int*)ei)[e];
                dst[i] = ((const int*)ei)[(long)E + e];
            }
        } else dst[i] = -1;
    }
    __syncthreads();
#pragma unroll
    for (int i = 0; i < 16; i++)
        if (dst[i] >= 0) atomicAdd(&cnt[dst[i] >> 8], 1);
    __syncthreads();
    int c0 = cnt[2 * tid], c1 = cnt[2 * tid + 1];
    int v = c0 + c1;
    ssum[tid] = v;
    __syncthreads();
    int val = v;
    for (int off = 1; off < 256; off <<= 1) {
        int t = (tid >= off) ? ssum[tid - off] : 0;
        __syncthreads();
        val += t;
        ssum[tid] = val;
        __syncthreads();
    }
    int excl = val - v;
    pfx[2 * tid] = excl;
    pfx[2 * tid + 1] = excl + c0;
    cur[2 * tid] = excl;
    cur[2 * tid + 1] = excl + c0;
    __syncthreads();
#pragma unroll
    for (int i = 0; i < 16; i++) {
        int d = dst[i];
        if (d >= 0) {
            int b = d >> 8;
            int p = atomicAdd(&cur[b], 1);
            sortw[p] = ((d & 255) << 20) | src[i];
            sortb[p] = (unsigned short)b;
        }
    }
    for (int b = tid; b < 512; b += 256) {
        int c = (b < NB) ? cnt[b] : 0;
        int base = c ? atomicAdd(&bin_cnt[b], c) : 0;
        dl[b] = base - pfx[b];
    }
    __syncthreads();
    for (int i = tid; i < total; i += 256) {
        int b = sortb[i];
        int pib = dl[b] + i;
        if (pib < BCAP) bin[(long)b * BCAP + pib] = sortw[i];
    }
}

// ---- gemm1 body: X[N,128] @ W1 -> h1t (bf16, UNSCALED). B-fragments from
//      precomputed global Wf1 (L2-resident, coalesced bf16x8); no LDS, no barrier.
__device__ __forceinline__ void gemm1_body(const void* __restrict__ A,
                                           const unsigned short* __restrict__ Wf1,
                                           unsigned short* __restrict__ ht, int N,
                                           const int* __restrict__ flags, int bid) {
    int tid = threadIdx.x;
    bool af32 = flags[0] != 0;

    int wave = tid >> 6, lane = tid & 63;
    int mrow = lane & 15, kq = lane >> 4;
    long row0 = (long)bid * 64 + wave * 16;
    long row = row0 + mrow;
    bool valid = row < N;

    f32x4 acc[8];
#pragma unroll
    for (int ct = 0; ct < 8; ct++) acc[ct] = (f32x4){0.f, 0.f, 0.f, 0.f};

    for (int kc = 0; kc < 4; kc++) {
        bf16x8 a = {0, 0, 0, 0, 0, 0, 0, 0};
        if (valid) {
            if (af32) {
                const float* ap = (const float*)A + row * 128 + kc * 32 + kq * 8;
                float4 f0 = *(const float4*)ap;
                float4 f1 = *(const float4*)(ap + 4);
                a[0] = (short)f2bf(f0.x); a[1] = (short)f2bf(f0.y);
                a[2] = (short)f2bf(f0.z); a[3] = (short)f2bf(f0.w);
                a[4] = (short)f2bf(f1.x); a[5] = (short)f2bf(f1.y);
                a[6] = (short)f2bf(f1.z); a[7] = (short)f2bf(f1.w);
            } else {
                a = *(const bf16x8*)((const unsigned short*)A + row * 128 + kc * 32 + kq * 8);
            }
        }
#pragma unroll
        for (int ct = 0; ct < 8; ct++) {
            bf16x8 b = *(const bf16x8*)(Wf1 + ((kc * 8 + ct) * 64 + lane) * 8);
            acc[ct] = __builtin_amdgcn_mfma_f32_16x16x32_bf16(a, b, acc[ct], 0, 0, 0);
        }
    }
#pragma unroll
    for (int ct = 0; ct < 8; ct++) {
#pragma unroll
        for (int r = 0; r < 4; r++) {
            long orow = row0 + kq * 4 + r;
            if (orow < N) ht[orow * 128 + ct * 16 + mrow] = f2bf(acc[ct][r]);
        }
    }
}

// ---- binB body: per-bucket CSR build in LDS; adj staged, coalesced write ----
__device__ __forceinline__ void binB_body(const int* __restrict__ bin_cnt,
                                          const int* __restrict__ bin,
                                          int* __restrict__ deg_i, int* __restrict__ row_start,
                                          float* __restrict__ dinv, int* __restrict__ adj,
                                          int* gctr, int N, int b) {
    __shared__ int deg[256];
    __shared__ int sm[256];
    __shared__ int cur[256];
    __shared__ int sadj[BCAP];
    __shared__ int sbase;
    int tid = threadIdx.x;
    int cnt = min(bin_cnt[b], BCAP);
    const int* bp = bin + (long)b * BCAP;
    deg[tid] = 0;
    __syncthreads();
    for (int i = tid; i < cnt; i += 256)
        atomicAdd(&deg[bp[i] >> 20], 1);
    __syncthreads();
    int d = deg[tid];
    int val = d;
    sm[tid] = val;
    __syncthreads();
    for (int off = 1; off < 256; off <<= 1) {
        int t = (tid >= off) ? sm[tid - off] : 0;
        __syncthreads();
        val += t;
        sm[tid] = val;
        __syncthreads();
    }
    if (tid == 255) sbase = atomicAdd(gctr, val);
    __syncthreads();
    int lstart = val - d;
    cur[tid] = lstart;
    int n = (b << 8) + tid;
    if (n < N) {
        deg_i[n] = d;
        row_start[n] = sbase + lstart;
        dinv[n] = rsqrtf((float)(d + 1));
    }
    __syncthreads();
    for (int i = tid; i < cnt; i += 256) {
        int w = bp[i];
        int pos = atomicAdd(&cur[w >> 20], 1);
        sadj[pos] = w & 0xFFFFF;
    }
    __syncthreads();
    for (int i = tid; i < cnt; i += 256)
        adj[sbase + i] = sadj[i];
}

// ---- front1: binA + first half of gemm1 (independent work, fat dispatch) ----
__global__ __launch_bounds__(256) void k_front1(
    const void* __restrict__ ei, int* __restrict__ bin_cnt, int* __restrict__ bin,
    int E, int NB, const int* __restrict__ flags,
    const void* __restrict__ xr, const unsigned short* __restrict__ Wf1,
    unsigned short* __restrict__ h1t, int N, int gA)
{
    __shared__ __align__(16) int smem[8448];   // binA arena
    if ((int)blockIdx.x < gA)
        binA_body(smem, ei, bin_cnt, bin, E, NB, flags);
    else
        gemm1_body(xr, Wf1, h1t, N, flags, (int)blockIdx.x - gA);
}

// ---- front2: binB + second half of gemm1. binB alone was 391 blocks / 35KB
//      LDS / ~19% occ serialized on the critical path; gemm1's second half
//      fills the machine while binB runs. gemm1 here does not depend on binB.
__global__ __launch_bounds__(256) void k_front2(
    const int* __restrict__ bin_cnt, const int* __restrict__ bin,
    int* __restrict__ deg_i, int* __restrict__ row_start,
    float* __restrict__ dinv, int* __restrict__ adj, int* gctr, int N,
    const void* __restrict__ xr, const unsigned short* __restrict__ Wf1,
    unsigned short* __restrict__ h1t, const int* __restrict__ flags,
    int NBb, int g1off)
{
    if ((int)blockIdx.x < NBb)
        binB_body(bin_cnt, bin, deg_i, row_start, dinv, adj, gctr, N, (int)blockIdx.x);
    else
        gemm1_body(xr, Wf1, h1t, N, flags, g1off + (int)blockIdx.x - NBb);
}

// ---- layer-1 gather + MFMA layer-2 fusion, BARRIER-FREE block tile.
//      Each wave gathers 4 nodes into its own 4 rows of the shared 16x128
//      tile, then runs the full 4-MFMA tail itself and stores ONLY the D-rows
//      with kq==wave. Those D-rows depend solely on A-rows 4w..4w+3 = this
//      wave's own LDS writes (same-wave lgkmcnt ordering). Rows of other waves
//      may be garbage/in-flux when read — they feed only discarded D rows
//      (D-row m depends only on A-row m). MFMA cost x4 (still ~1% util, free);
//      __syncthreads and its wave-variance wait eliminated.
__global__ __launch_bounds__(256) void k_gather128(
    const unsigned short* __restrict__ h1t, const int* __restrict__ row_start,
    const int* __restrict__ deg_i, const float* __restrict__ dinv,
    const float* __restrict__ bb1, const int* __restrict__ adj,
    const unsigned short* __restrict__ Wf2, unsigned short* __restrict__ h2t, int N)
{
    __shared__ unsigned short tile[16 * 128];   // 4KB block tile, per-wave strips
    int tid = threadIdx.x;
    int wave = tid >> 6, lane = tid & 63;
    int g = lane >> 4, c = lane & 15;

    long nb = (long)blockIdx.x * 16;            // block's 16-node tile base
    if (nb >= N) return;                        // block-uniform early out (no barrier)

    for (int i = 0; i < 4; i++) {
        int it = wave * 4 + i;                  // this wave's row within tile
        long n = nb + it;
        if (n < N) {
            int cnt = deg_i[n];
            int start = row_start[n];
            int L = cnt + 1;                    // virtual list: neighbors + self

            f32x2 ac[4];
#pragma unroll
            for (int t = 0; t < 4; t++) { ac[t].x = 0.f; ac[t].y = 0.f; }

            for (int jb = 0; jb < L; jb += 64) {
                int idx = jb + lane;
                int av = (idx < cnt) ? adj[start + idx] : (int)n;
                int take = min(L - jb, 64);
                for (int jj = 0; jj < take; jj += 8) {
                    int r0 = __shfl(av, jj + g);
                    int r1 = __shfl(av, jj + 4 + g);
                    bool m0 = (jj + g) < take;
                    bool m1 = (jj + 4 + g) < take;
                    float d0 = dinv[r0];        // L2-resident broadcast
                    float d1 = dinv[r1];
                    uint4 v0 = make_uint4(0, 0, 0, 0), v1 = make_uint4(0, 0, 0, 0);
                    if (m0) v0 = *(const uint4*)(h1t + (long)r0 * 128 + c * 8);
                    if (m1) v1 = *(const uint4*)(h1t + (long)r1 * 128 + c * 8);
                    acc8sp(ac, v0, d0);
                    acc8sp(ac, v1, d1);
                }
            }
#pragma unroll
            for (int t = 0; t < 4; t++) {
                ac[t].x += __shfl_xor(ac[t].x, 16); ac[t].y += __shfl_xor(ac[t].y, 16);
                ac[t].x += __shfl_xor(ac[t].x, 32); ac[t].y += __shfl_xor(ac[t].y, 32);
            }
            if (g == 0) {
                float dv = dinv[n];
                float4 bA = *(const float4*)(bb1 + c * 8);
                float4 bB = *(const float4*)(bb1 + c * 8 + 4);
                float h0 = fmaxf(ac[0].x * dv + bA.x, 0.f);
                float h1 = fmaxf(ac[0].y * dv + bA.y, 0.f);
                float h2 = fmaxf(ac[1].x * dv + bA.z, 0.f);
                float h3 = fmaxf(ac[1].y * dv + bA.w, 0.f);
                float h4 = fmaxf(ac[2].x * dv + bB.x, 0.f);
                float h5 = fmaxf(ac[2].y * dv + bB.y, 0.f);
                float h6 = fmaxf(ac[3].x * dv + bB.z, 0.f);
                float h7 = fmaxf(ac[3].y * dv + bB.w, 0.f);
                uint4 pv;
                pv.x = (unsigned)f2bf(h0) | ((unsigned)f2bf(h1) << 16);
                pv.y = (unsigned)f2bf(h2) | ((unsigned)f2bf(h3) << 16);
                pv.z = (unsigned)f2bf(h4) | ((unsigned)f2bf(h5) << 16);
                pv.w = (unsigned)f2bf(h6) | ((unsigned)f2bf(h7) << 16);
                *(uint4*)(tile + it * 128 + ((c ^ it) * 8)) = pv;   // swizzled chunk
            }
        }
    }

    // ---- per-wave MFMA tail (no barrier): store only kq==wave D-rows.
    int mrow = lane & 15, kq = lane >> 4;
    f32x4 acc = (f32x4){0.f, 0.f, 0.f, 0.f};
#pragma unroll
    for (int kc = 0; kc < 4; kc++) {
        bf16x8 a = *(const bf16x8*)(tile + mrow * 128 + (((kc * 4 + kq) ^ mrow) * 8));
        bf16x8 b = *(const bf16x8*)(Wf2 + (kc * 64 + lane) * 8);
        acc = __builtin_amdgcn_mfma_f32_16x16x32_bf16(a, b, acc, 0, 0, 0);
    }
    if (kq == wave) {
#pragma unroll
        for (int r = 0; r < 4; r++) {
            long orow = nb + kq * 4 + r;
            if (orow < N) h2t[orow * 16 + mrow] = f2bf(acc[r] * dinv[orow]);
        }
    }
}

// ---- layer-2 gather + log_softmax: one node per LANE-PAIR (32 nodes/wave)
__global__ __launch_bounds__(256) void k_gather16(
    const unsigned short* __restrict__ h2t, const int* __restrict__ row_start,
    const int* __restrict__ deg_i, const float* __restrict__ dinv,
    const float* __restrict__ bb2, const int* __restrict__ adj,
    void* __restrict__ out, int N, const int* __restrict__ flags)
{
    int tid = threadIdx.x;
    int wave = tid >> 6, lane = tid & 63;
    int half = lane & 1;
    int n = (blockIdx.x * 4 + wave) * 32 + (lane >> 1);
    bool valid = n < N;
    int cnt = valid ? deg_i[n] : 0;
    int start = valid ? row_start[n] : 0;

    f32x2 ac[4];
#pragma unroll
    for (int t = 0; t < 4; t++) { ac[t].x = 0.f; ac[t].y = 0.f; }

    int j = 0;
    for (; j + 2 <= cnt; j += 2) {
        int s0 = adj[start + j];
        int s1 = adj[start + j + 1];
        uint4 v0 = *(const uint4*)(h2t + (long)s0 * 16 + half * 8);
        uint4 v1 = *(const uint4*)(h2t + (long)s1 * 16 + half * 8);
        acc8p(ac, v0);
        acc8p(ac, v1);
    }
    if (j < cnt) {
        int s = adj[start + j];
        uint4 v = *(const uint4*)(h2t + (long)s * 16 + half * 8);
        acc8p(ac, v);
    }
    if (!valid) return;
    {   // self-loop
        uint4 v = *(const uint4*)(h2t + (long)n * 16 + half * 8);
        acc8p(ac, v);
    }
    float dv = dinv[n];
    float4 bA = *(const float4*)(bb2 + half * 8);
    float4 bB = *(const float4*)(bb2 + half * 8 + 4);
    float vv[8];
    vv[0] = ac[0].x * dv + bA.x; vv[1] = ac[0].y * dv + bA.y;
    vv[2] = ac[1].x * dv + bA.z; vv[3] = ac[1].y * dv + bA.w;
    vv[4] = ac[2].x * dv + bB.x; vv[5] = ac[2].y * dv + bB.y;
    vv[6] = ac[3].x * dv + bB.z; vv[7] = ac[3].y * dv + bB.w;
    float m8 = vv[0];
#pragma unroll
    for (int k = 1; k < 8; k++) m8 = fmaxf(m8, vv[k]);
    float m16 = fmaxf(m8, __shfl_xor(m8, 1));
    float s8 = 0.f;
#pragma unroll
    for (int k = 0; k < 8; k++) s8 += __expf(vv[k] - m16);
    float s16 = s8 + __shfl_xor(s8, 1);
    float lg = __logf(s16);
    if (flags[0]) {
        float* o = (float*)out + (long)n * 16 + half * 8;
        *(float4*)o = make_float4(vv[0] - m16 - lg, vv[1] - m16 - lg, vv[2] - m16 - lg, vv[3] - m16 - lg);
        *(float4*)(o + 4) = make_float4(vv[4] - m16 - lg, vv[5] - m16 - lg, vv[6] - m16 - lg, vv[7] - m16 - lg);
    } else {
        uint4 pv;
        pv.x = (unsigned)f2bf(vv[0] - m16 - lg) | ((unsigned)f2bf(vv[1] - m16 - lg) << 16);
        pv.y = (unsigned)f2bf(vv[2] - m16 - lg) | ((unsigned)f2bf(vv[3] - m16 - lg) << 16);
        pv.z = (unsigned)f2bf(vv[4] - m16 - lg) | ((unsigned)f2bf(vv[5] - m16 - lg) << 16);
        pv.w = (unsigned)f2bf(vv[6] - m16 - lg) | ((unsigned)f2bf(vv[7] - m16 - lg) << 16);
        *(uint4*)((unsigned short*)out + (long)n * 16 + half * 8) = pv;
    }
}

static inline size_t alignup(size_t x) { return (x + 255) & ~(size_t)255; }

extern "C" void kernel_launch(void* const* d_in, const int* in_sizes, int n_in,
                              void* d_out, int out_size, void* d_ws, size_t ws_size,
                              hipStream_t stream) {
    const void* xr  = d_in[0];
    const void* ei  = d_in[1];
    const void* W1r = d_in[2];
    const void* b1r = d_in[3];
    const void* W2r = d_in[4];
    const void* b2r = d_in[5];

    int N = in_sizes[0] / 128;
    int E = in_sizes[1] / 2;
    int NB = (N + 255) >> 8;

    char* w = (char*)d_ws;
    size_t off = 0;
    int*   flags = (int*)(w + off);   off += 256;      // flags[0..1]; gctr at flags[16]
    int*   gctr  = flags + 16;
    int*   deg_i = (int*)(w + off);   off = alignup(off + (size_t)N * 4);
    int*   row_start = (int*)(w + off); off = alignup(off + (size_t)N * 4);
    float* dinv  = (float*)(w + off); off = alignup(off + (size_t)N * 4);
    float* bb1   = (float*)(w + off); off = alignup(off + 128 * 4);
    float* bb2   = (float*)(w + off); off = alignup(off + 16 * 4);
    unsigned short* Wf1 = (unsigned short*)(w + off); off = alignup(off + 16384 * 2);
    unsigned short* Wf2 = (unsigned short*)(w + off); off = alignup(off + 2048 * 2);
    int*   bin_cnt = (int*)(w + off); off = alignup(off + (size_t)NB * 4);
    int*   adj   = (int*)(w + off);   off = alignup(off + (size_t)E * 4);
    unsigned short* h1t = (unsigned short*)(w + off); off = alignup(off + (size_t)N * 128 * 2);
    unsigned short* h2t = (unsigned short*)(w + off); off = alignup(off + (size_t)N * 16 * 2);
    int*   bin   = (int*)(w + off);   off = alignup(off + (size_t)NB * BCAP * 4);

    int gG = (N + 63) / 64;            // total gemm1 blocks
    int g1a = gG / 2;                  // first half -> front1
    int g1b = gG - g1a;                // second half -> front2 (overlaps binB)
    int gA = (E + 4095) / 4096;
    int gW = (N + 15) / 16;            // block-level 16-node tile, 4 waves x 4 nodes
    int gP = (N + 127) / 128;

    k_setup<<<12, 256, 0, stream>>>(W1r, W2r, b1r, b2r, (const unsigned int*)ei,
                                    Wf1, Wf2, bb1, bb2, bin_cnt, gctr, flags, NB);
    k_front1<<<gA + g1a, 256, 0, stream>>>(ei, bin_cnt, bin, E, NB, flags,
                                           xr, Wf1, h1t, N, gA);
    k_front2<<<NB + g1b, 256, 0, stream>>>(bin_cnt, bin, deg_i, row_start, dinv,
                                           adj, gctr, N, xr, Wf1, h1t, flags,
                                           NB, g1a);
    k_gather128<<<gW, 256, 0, stream>>>(h1t, row_start, deg_i, dinv, bb1, adj, Wf2, h2t, N);
    k_gather16<<<gP, 256, 0, stream>>>(h2t, row_start, deg_i, dinv, bb2, adj, d_out, N, flags);
}

// Round 12
// 224.854 us; speedup vs baseline: 1.0289x; 1.0289x over previous
//
#include <hip/hip_runtime.h>
#include <hip/hip_bf16.h>

typedef short bf16x8 __attribute__((ext_vector_type(8)));
typedef float f32x4 __attribute__((ext_vector_type(4)));
typedef float f32x2 __attribute__((ext_vector_type(2)));

#define BCAP 8192   // per-bucket bin capacity (mean ~4096 for E=1.6M, NB=391)

// LEDGER (rounds 1-11):
// - Lane-reduce W2 fusion: 3 variants, all lose >=28us vs MFMA. Don't re-fuse that way.
// - Inline-asm pk ops destroy load hoisting (r1); plain-C f32x2 neutral (r6).
// - gather128 is NOT VALU-bound (r6 neutral), NOT scalar-L2-load bound (r9
//   neutral), NOT barrier-bound (r10: removing barrier was -3us WORSE).
//   VALU 54% / HBM 36% / occ 68% => LATENCY-bound. r11/r12 lever: per-lane MLP
//   2 -> 4 in-flight uint4 loads in the gather loop.
// - Wave count must be >~3x the 8192 slots for dynamic refill (r4, r7).
// - r8/r9 block 16-node tile + barrier + wave-0 MFMA tail = best (228.8/229.9);
//   r10's barrier-free x4-MFMA tail regressed — REVERTED.
// - r11 bench was an infra failure (container died twice); r12 = identical
//   resubmit of the 4-deep-ILP experiment. Do not stack untested changes.

__device__ inline float bf2f(unsigned short u) {
    union { unsigned int i; float f; } v; v.i = ((unsigned int)u) << 16; return v.f;
}
__device__ inline unsigned short f2bf(float f) {
    union { float f; unsigned int i; } v; v.f = f;
    unsigned int r = v.i + 0x7FFFu + ((v.i >> 16) & 1u);
    return (unsigned short)(r >> 16);
}
__device__ inline float u_lo(unsigned u) {
    union { unsigned i; float f; } v; v.i = u << 16; return v.f;
}
__device__ inline float u_hi(unsigned u) {
    union { unsigned i; float f; } v; v.i = u & 0xFFFF0000u; return v.f;
}
__device__ inline void acc8p(f32x2* ac, uint4 v) {
    f32x2 t;
    t.x = u_lo(v.x); t.y = u_hi(v.x); ac[0] += t;
    t.x = u_lo(v.y); t.y = u_hi(v.y); ac[1] += t;
    t.x = u_lo(v.z); t.y = u_hi(v.z); ac[2] += t;
    t.x = u_lo(v.w); t.y = u_hi(v.w); ac[3] += t;
}
__device__ inline void acc8sp(f32x2* ac, uint4 v, float d) {   // ac += d*v
    f32x2 dd; dd.x = d; dd.y = d;
    f32x2 t;
    t.x = u_lo(v.x); t.y = u_hi(v.x); ac[0] += t * dd;
    t.x = u_lo(v.y); t.y = u_hi(v.y); ac[1] += t * dd;
    t.x = u_lo(v.z); t.y = u_hi(v.z); ac[2] += t * dd;
    t.x = u_lo(v.w); t.y = u_hi(v.w); ac[3] += t * dd;
}

// ---- fused setup: fragment-table precompute + bias conversion + init + flags.
__global__ __launch_bounds__(256) void k_setup(
    const void* __restrict__ W1r, const void* __restrict__ W2r,
    const void* __restrict__ b1r, const void* __restrict__ b2r,
    const unsigned int* __restrict__ eiraw,
    unsigned short* __restrict__ Wf1, unsigned short* __restrict__ Wf2,
    float* __restrict__ bb1, float* __restrict__ bb2,
    int* __restrict__ bin_cnt, int* gctr, int* flags, int NB)
{
    __shared__ int cs, ce;
    int blk = blockIdx.x, tid = threadIdx.x;
    const unsigned short* w1u = (const unsigned short*)W1r;
    int lf = 0;
    for (int i = tid; i < 4096; i += 256) {
        unsigned e = (w1u[i] >> 7) & 0xFF;
        lf += (e >= 0x90);               // |val| >= 2^17: impossible for real bf16 weights
    }
    for (int o = 32; o; o >>= 1) lf += __shfl_down(lf, o);
    if (tid == 0) { cs = 0; ce = 0; }
    __syncthreads();
    if ((tid & 63) == 0 && lf) atomicAdd(&cs, lf);
    __syncthreads();
    bool isf32 = cs > 16;
    const float* w1f = (const float*)W1r;
    const unsigned short* w1b = (const unsigned short*)W1r;
    const float* w2f = (const float*)W2r;
    const unsigned short* w2b = (const unsigned short*)W2r;

    if (blk < 8) {                       // Wf1: 2048 fragment entries x 8 shorts
        int idx = blk * 256 + tid;
        int kc = idx >> 9, rem = idx & 511;
        int ct = rem >> 6, l = rem & 63;
        int n = ct * 16 + (l & 15);
        int kbase = kc * 32 + (l >> 4) * 8;
        unsigned short* d = &Wf1[idx * 8];
#pragma unroll
        for (int j = 0; j < 8; j++) {
            int s = (kbase + j) * 128 + n;
            d[j] = isf32 ? f2bf(w1f[s]) : w1b[s];
        }
    } else if (blk == 8) {               // Wf2: 256 entries x 8 shorts
        int idx = tid;
        int kc = idx >> 6, l = idx & 63;
        int mrow = l & 15, kq = l >> 4;
        unsigned short* d = &Wf2[idx * 8];
#pragma unroll
        for (int j = 0; j < 8; j++) {
            int s = (kc * 32 + kq * 8 + j) * 16 + mrow;
            d[j] = isf32 ? f2bf(w2f[s]) : w2b[s];
        }
    } else if (blk == 9) {
        if (tid < 128) bb1[tid] = isf32 ? ((const float*)b1r)[tid] : bf2f(((const unsigned short*)b1r)[tid]);
        else if (tid < 144) bb2[tid - 128] = isf32 ? ((const float*)b2r)[tid - 128] : bf2f(((const unsigned short*)b2r)[tid - 128]);
    } else if (blk == 10) {
        for (int i = tid; i < NB; i += 256) bin_cnt[i] = 0;
        if (tid == 0) *gctr = 0;
    } else {                             // blk == 11: flags
        int le = 0;
        for (int i = tid; i < 128; i += 256)
            if ((i & 1) && eiraw[i] != 0) le++;
        for (int o = 32; o; o >>= 1) le += __shfl_down(le, o);
        if ((tid & 63) == 0 && le) atomicAdd(&ce, le);
        __syncthreads();
        if (tid == 0) { flags[0] = isf32 ? 1 : 0; flags[1] = (ce == 0) ? 1 : 0; }
    }
}

// ---- binA body: LDS bucket-sort 4096 edges, coalesced run-writes into bin ----
__device__ __forceinline__ void binA_body(int* smem, const void* __restrict__ ei,
                                          int* __restrict__ bin_cnt, int* __restrict__ bin,
                                          int E, int NB, const int* __restrict__ flags) {
    int* cnt  = smem;                     // 512
    int* pfx  = smem + 512;               // 512
    int* cur  = smem + 1024;              // 512
    int* dl   = smem + 1536;              // 512
    int* ssum = smem + 2048;              // 256
    int* sortw = smem + 2304;             // 4096
    unsigned short* sortb = (unsigned short*)(smem + 6400);   // 4096 shorts
    int tid = threadIdx.x;
    for (int i = tid; i < 512; i += 256) cnt[i] = 0;
    bool i64 = flags[1] != 0;
    long e0 = (long)blockIdx.x * 4096;
    int total = (int)min((long)4096, (long)E - e0);
    int src[16], dst[16];
#pragma unroll
    for (int i = 0; i < 16; i++) {
        long e = e0 + i * 256 + tid;
        if (e < E) {
            if (i64) {
                src[i] = (int)((const long long*)ei)[e];
                dst[i] = (int)((const long long*)ei)[(long)E + e];
            } else {
                src[i] = ((const int*)ei)[e];
                dst[i] = ((const int*)ei)[(long)E + e];
            }
        } else dst[i] = -1;
    }
    __syncthreads();
#pragma unroll
    for (int i = 0; i < 16; i++)
        if (dst[i] >= 0) atomicAdd(&cnt[dst[i] >> 8], 1);
    __syncthreads();
    int c0 = cnt[2 * tid], c1 = cnt[2 * tid + 1];
    int v = c0 + c1;
    ssum[tid] = v;
    __syncthreads();
    int val = v;
    for (int off = 1; off < 256; off <<= 1) {
        int t = (tid >= off) ? ssum[tid - off] : 0;
        __syncthreads();
        val += t;
        ssum[tid] = val;
        __syncthreads();
    }
    int excl = val - v;
    pfx[2 * tid] = excl;
    pfx[2 * tid + 1] = excl + c0;
    cur[2 * tid] = excl;
    cur[2 * tid + 1] = excl + c0;
    __syncthreads();
#pragma unroll
    for (int i = 0; i < 16; i++) {
        int d = dst[i];
        if (d >= 0) {
            int b = d >> 8;
            int p = atomicAdd(&cur[b], 1);
            sortw[p] = ((d & 255) << 20) | src[i];
            sortb[p] = (unsigned short)b;
        }
    }
    for (int b = tid; b < 512; b += 256) {
        int c = (b < NB) ? cnt[b] : 0;
        int base = c ? atomicAdd(&bin_cnt[b], c) : 0;
        dl[b] = base - pfx[b];
    }
    __syncthreads();
    for (int i = tid; i < total; i += 256) {
        int b = sortb[i];
        int pib = dl[b] + i;
        if (pib < BCAP) bin[(long)b * BCAP + pib] = sortw[i];
    }
}

// ---- gemm1 body: X[N,128] @ W1 -> h1t (bf16, UNSCALED). B-fragments from
//      precomputed global Wf1 (L2-resident, coalesced bf16x8); no LDS, no barrier.
__device__ __forceinline__ void gemm1_body(const void* __restrict__ A,
                                           const unsigned short* __restrict__ Wf1,
                                           unsigned short* __restrict__ ht, int N,
                                           const int* __restrict__ flags, int bid) {
    int tid = threadIdx.x;
    bool af32 = flags[0] != 0;

    int wave = tid >> 6, lane = tid & 63;
    int mrow = lane & 15, kq = lane >> 4;
    long row0 = (long)bid * 64 + wave * 16;
    long row = row0 + mrow;
    bool valid = row < N;

    f32x4 acc[8];
#pragma unroll
    for (int ct = 0; ct < 8; ct++) acc[ct] = (f32x4){0.f, 0.f, 0.f, 0.f};

    for (int kc = 0; kc < 4; kc++) {
        bf16x8 a = {0, 0, 0, 0, 0, 0, 0, 0};
        if (valid) {
            if (af32) {
                const float* ap = (const float*)A + row * 128 + kc * 32 + kq * 8;
                float4 f0 = *(const float4*)ap;
                float4 f1 = *(const float4*)(ap + 4);
                a[0] = (short)f2bf(f0.x); a[1] = (short)f2bf(f0.y);
                a[2] = (short)f2bf(f0.z); a[3] = (short)f2bf(f0.w);
                a[4] = (short)f2bf(f1.x); a[5] = (short)f2bf(f1.y);
                a[6] = (short)f2bf(f1.z); a[7] = (short)f2bf(f1.w);
            } else {
                a = *(const bf16x8*)((const unsigned short*)A + row * 128 + kc * 32 + kq * 8);
            }
        }
#pragma unroll
        for (int ct = 0; ct < 8; ct++) {
            bf16x8 b = *(const bf16x8*)(Wf1 + ((kc * 8 + ct) * 64 + lane) * 8);
            acc[ct] = __builtin_amdgcn_mfma_f32_16x16x32_bf16(a, b, acc[ct], 0, 0, 0);
        }
    }
#pragma unroll
    for (int ct = 0; ct < 8; ct++) {
#pragma unroll
        for (int r = 0; r < 4; r++) {
            long orow = row0 + kq * 4 + r;
            if (orow < N) ht[orow * 128 + ct * 16 + mrow] = f2bf(acc[ct][r]);
        }
    }
}

// ---- binB body: per-bucket CSR build in LDS; adj staged, coalesced write ----
__device__ __forceinline__ void binB_body(const int* __restrict__ bin_cnt,
                                          const int* __restrict__ bin,
                                          int* __restrict__ deg_i, int* __restrict__ row_start,
                                          float* __restrict__ dinv, int* __restrict__ adj,
                                          int* gctr, int N, int b) {
    __shared__ int deg[256];
    __shared__ int sm[256];
    __shared__ int cur[256];
    __shared__ int sadj[BCAP];
    __shared__ int sbase;
    int tid = threadIdx.x;
    int cnt = min(bin_cnt[b], BCAP);
    const int* bp = bin + (long)b * BCAP;
    deg[tid] = 0;
    __syncthreads();
    for (int i = tid; i < cnt; i += 256)
        atomicAdd(&deg[bp[i] >> 20], 1);
    __syncthreads();
    int d = deg[tid];
    int val = d;
    sm[tid] = val;
    __syncthreads();
    for (int off = 1; off < 256; off <<= 1) {
        int t = (tid >= off) ? sm[tid - off] : 0;
        __syncthreads();
        val += t;
        sm[tid] = val;
        __syncthreads();
    }
    if (tid == 255) sbase = atomicAdd(gctr, val);
    __syncthreads();
    int lstart = val - d;
    cur[tid] = lstart;
    int n = (b << 8) + tid;
    if (n < N) {
        deg_i[n] = d;
        row_start[n] = sbase + lstart;
        dinv[n] = rsqrtf((float)(d + 1));
    }
    __syncthreads();
    for (int i = tid; i < cnt; i += 256) {
        int w = bp[i];
        int pos = atomicAdd(&cur[w >> 20], 1);
        sadj[pos] = w & 0xFFFFF;
    }
    __syncthreads();
    for (int i = tid; i < cnt; i += 256)
        adj[sbase + i] = sadj[i];
}

// ---- front1: binA + first half of gemm1 (independent work, fat dispatch) ----
__global__ __launch_bounds__(256) void k_front1(
    const void* __restrict__ ei, int* __restrict__ bin_cnt, int* __restrict__ bin,
    int E, int NB, const int* __restrict__ flags,
    const void* __restrict__ xr, const unsigned short* __restrict__ Wf1,
    unsigned short* __restrict__ h1t, int N, int gA)
{
    __shared__ __align__(16) int smem[8448];   // binA arena
    if ((int)blockIdx.x < gA)
        binA_body(smem, ei, bin_cnt, bin, E, NB, flags);
    else
        gemm1_body(xr, Wf1, h1t, N, flags, (int)blockIdx.x - gA);
}

// ---- front2: binB + second half of gemm1 (binB alone is underoccupied) ----
__global__ __launch_bounds__(256) void k_front2(
    const int* __restrict__ bin_cnt, const int* __restrict__ bin,
    int* __restrict__ deg_i, int* __restrict__ row_start,
    float* __restrict__ dinv, int* __restrict__ adj, int* gctr, int N,
    const void* __restrict__ xr, const unsigned short* __restrict__ Wf1,
    unsigned short* __restrict__ h1t, const int* __restrict__ flags,
    int NBb, int g1off)
{
    if ((int)blockIdx.x < NBb)
        binB_body(bin_cnt, bin, deg_i, row_start, dinv, adj, gctr, N, (int)blockIdx.x);
    else
        gemm1_body(xr, Wf1, h1t, N, flags, g1off + (int)blockIdx.x - NBb);
}

// ---- layer-1 gather + MFMA layer-2 fusion, block-level 16-node tile
//      (r8/r9 verified: barrier + wave-0 tail). r11/r12 change: gather inner
//      loop deepened to 4 in-flight uint4 loads per lane (jj step 16) — the
//      kernel is latency-bound (VALU 54%, HBM 36%, occ 68%), so doubling
//      per-lane outstanding bytes should raise delivered bandwidth.
__global__ __launch_bounds__(256) void k_gather128(
    const unsigned short* __restrict__ h1t, const int* __restrict__ row_start,
    const int* __restrict__ deg_i, const float* __restrict__ dinv,
    const float* __restrict__ bb1, const int* __restrict__ adj,
    const unsigned short* __restrict__ Wf2, unsigned short* __restrict__ h2t, int N)
{
    __shared__ unsigned short tile[16 * 128];   // 4KB block tile
    int tid = threadIdx.x;
    int wave = tid >> 6, lane = tid & 63;
    int g = lane >> 4, c = lane & 15;

    long nb = (long)blockIdx.x * 16;            // block's 16-node tile base
    if (nb >= N) return;                        // block-uniform early out

    for (int i = 0; i < 4; i++) {
        int it = wave * 4 + i;                  // row within tile
        long n = nb + it;
        if (n < N) {
            int cnt = deg_i[n];
            int start = row_start[n];
            int L = cnt + 1;                    // virtual list: neighbors + self

            f32x2 ac[4];
#pragma unroll
            for (int t = 0; t < 4; t++) { ac[t].x = 0.f; ac[t].y = 0.f; }

            for (int jb = 0; jb < L; jb += 64) {
                int idx = jb + lane;
                int av = (idx < cnt) ? adj[start + idx] : (int)n;
                int take = min(L - jb, 64);
                for (int jj = 0; jj < take; jj += 16) {
                    int r0 = __shfl(av, jj + g);
                    int r1 = __shfl(av, jj + 4 + g);
                    int r2 = __shfl(av, jj + 8 + g);
                    int r3 = __shfl(av, jj + 12 + g);
                    bool m0 = (jj + g) < take;
                    bool m1 = (jj + 4 + g) < take;
                    bool m2 = (jj + 8 + g) < take;
                    bool m3 = (jj + 12 + g) < take;
                    float d0 = dinv[r0];        // r always a valid node id
                    float d1 = dinv[r1];
                    float d2 = dinv[r2];
                    float d3 = dinv[r3];
                    uint4 v0 = make_uint4(0, 0, 0, 0), v1 = make_uint4(0, 0, 0, 0);
                    uint4 v2 = make_uint4(0, 0, 0, 0), v3 = make_uint4(0, 0, 0, 0);
                    if (m0) v0 = *(const uint4*)(h1t + (long)r0 * 128 + c * 8);
                    if (m1) v1 = *(const uint4*)(h1t + (long)r1 * 128 + c * 8);
                    if (m2) v2 = *(const uint4*)(h1t + (long)r2 * 128 + c * 8);
                    if (m3) v3 = *(const uint4*)(h1t + (long)r3 * 128 + c * 8);
                    acc8sp(ac, v0, d0);
                    acc8sp(ac, v1, d1);
                    acc8sp(ac, v2, d2);
                    acc8sp(ac, v3, d3);
                }
            }
#pragma unroll
            for (int t = 0; t < 4; t++) {
                ac[t].x += __shfl_xor(ac[t].x, 16); ac[t].y += __shfl_xor(ac[t].y, 16);
                ac[t].x += __shfl_xor(ac[t].x, 32); ac[t].y += __shfl_xor(ac[t].y, 32);
            }
            if (g == 0) {
                float dv = dinv[n];
                float4 bA = *(const float4*)(bb1 + c * 8);
                float4 bB = *(const float4*)(bb1 + c * 8 + 4);
                float h0 = fmaxf(ac[0].x * dv + bA.x, 0.f);
                float h1 = fmaxf(ac[0].y * dv + bA.y, 0.f);
                float h2 = fmaxf(ac[1].x * dv + bA.z, 0.f);
                float h3 = fmaxf(ac[1].y * dv + bA.w, 0.f);
                float h4 = fmaxf(ac[2].x * dv + bB.x, 0.f);
                float h5 = fmaxf(ac[2].y * dv + bB.y, 0.f);
                float h6 = fmaxf(ac[3].x * dv + bB.z, 0.f);
                float h7 = fmaxf(ac[3].y * dv + bB.w, 0.f);
                uint4 pv;
                pv.x = (unsigned)f2bf(h0) | ((unsigned)f2bf(h1) << 16);
                pv.y = (unsigned)f2bf(h2) | ((unsigned)f2bf(h3) << 16);
                pv.z = (unsigned)f2bf(h4) | ((unsigned)f2bf(h5) << 16);
                pv.w = (unsigned)f2bf(h6) | ((unsigned)f2bf(h7) << 16);
                *(uint4*)(tile + it * 128 + ((c ^ it) * 8)) = pv;   // swizzled chunk
            }
        }
    }
    __syncthreads();

    // ---- MFMA tail (wave 0 only): tile[16][128] @ W2 -> h2t*dinv (r8 verified).
    if (wave == 0) {
        int mrow = lane & 15, kq = lane >> 4;
        f32x4 acc = (f32x4){0.f, 0.f, 0.f, 0.f};
#pragma unroll
        for (int kc = 0; kc < 4; kc++) {
            bf16x8 a = *(const bf16x8*)(tile + mrow * 128 + (((kc * 4 + kq) ^ mrow) * 8));
            bf16x8 b = *(const bf16x8*)(Wf2 + (kc * 64 + lane) * 8);
            acc = __builtin_amdgcn_mfma_f32_16x16x32_bf16(a, b, acc, 0, 0, 0);
        }
#pragma unroll
        for (int r = 0; r < 4; r++) {
            long orow = nb + kq * 4 + r;
            if (orow < N) h2t[orow * 16 + mrow] = f2bf(acc[r] * dinv[orow]);
        }
    }
}

// ---- layer-2 gather + log_softmax: one node per LANE-PAIR (32 nodes/wave)
__global__ __launch_bounds__(256) void k_gather16(
    const unsigned short* __restrict__ h2t, const int* __restrict__ row_start,
    const int* __restrict__ deg_i, const float* __restrict__ dinv,
    const float* __restrict__ bb2, const int* __restrict__ adj,
    void* __restrict__ out, int N, const int* __restrict__ flags)
{
    int tid = threadIdx.x;
    int wave = tid >> 6, lane = tid & 63;
    int half = lane & 1;
    int n = (blockIdx.x * 4 + wave) * 32 + (lane >> 1);
    bool valid = n < N;
    int cnt = valid ? deg_i[n] : 0;
    int start = valid ? row_start[n] : 0;

    f32x2 ac[4];
#pragma unroll
    for (int t = 0; t < 4; t++) { ac[t].x = 0.f; ac[t].y = 0.f; }

    int j = 0;
    for (; j + 2 <= cnt; j += 2) {
        int s0 = adj[start + j];
        int s1 = adj[start + j + 1];
        uint4 v0 = *(const uint4*)(h2t + (long)s0 * 16 + half * 8);
        uint4 v1 = *(const uint4*)(h2t + (long)s1 * 16 + half * 8);
        acc8p(ac, v0);
        acc8p(ac, v1);
    }
    if (j < cnt) {
        int s = adj[start + j];
        uint4 v = *(const uint4*)(h2t + (long)s * 16 + half * 8);
        acc8p(ac, v);
    }
    if (!valid) return;
    {   // self-loop
        uint4 v = *(const uint4*)(h2t + (long)n * 16 + half * 8);
        acc8p(ac, v);
    }
    float dv = dinv[n];
    float4 bA = *(const float4*)(bb2 + half * 8);
    float4 bB = *(const float4*)(bb2 + half * 8 + 4);
    float vv[8];
    vv[0] = ac[0].x * dv + bA.x; vv[1] = ac[0].y * dv + bA.y;
    vv[2] = ac[1].x * dv + bA.z; vv[3] = ac[1].y * dv + bA.w;
    vv[4] = ac[2].x * dv + bB.x; vv[5] = ac[2].y * dv + bB.y;
    vv[6] = ac[3].x * dv + bB.z; vv[7] = ac[3].y * dv + bB.w;
    float m8 = vv[0];
#pragma unroll
    for (int k = 1; k < 8; k++) m8 = fmaxf(m8, vv[k]);
    float m16 = fmaxf(m8, __shfl_xor(m8, 1));
    float s8 = 0.f;
#pragma unroll
    for (int k = 0; k < 8; k++) s8 += __expf(vv[k] - m16);
    float s16 = s8 + __shfl_xor(s8, 1);
    float lg = __logf(s16);
    if (flags[0]) {
        float* o = (float*)out + (long)n * 16 + half * 8;
        *(float4*)o = make_float4(vv[0] - m16 - lg, vv[1] - m16 - lg, vv[2] - m16 - lg, vv[3] - m16 - lg);
        *(float4*)(o + 4) = make_float4(vv[4] - m16 - lg, vv[5] - m16 - lg, vv[6] - m16 - lg, vv[7] - m16 - lg);
    } else {
        uint4 pv;
        pv.x = (unsigned)f2bf(vv[0] - m16 - lg) | ((unsigned)f2bf(vv[1] - m16 - lg) << 16);
        pv.y = (unsigned)f2bf(vv[2] - m16 - lg) | ((unsigned)f2bf(vv[3] - m16 - lg) << 16);
        pv.z = (unsigned)f2bf(vv[4] - m16 - lg) | ((unsigned)f2bf(vv[5] - m16 - lg) << 16);
        pv.w = (unsigned)f2bf(vv[6] - m16 - lg) | ((unsigned)f2bf(vv[7] - m16 - lg) << 16);
        *(uint4*)((unsigned short*)out + (long)n * 16 + half * 8) = pv;
    }
}

static inline size_t alignup(size_t x) { return (x + 255) & ~(size_t)255; }

extern "C" void kernel_launch(void* const* d_in, const int* in_sizes, int n_in,
                              void* d_out, int out_size, void* d_ws, size_t ws_size,
                              hipStream_t stream) {
    const void* xr  = d_in[0];
    const void* ei  = d_in[1];
    const void* W1r = d_in[2];
    const void* b1r = d_in[3];
    const void* W2r = d_in[4];
    const void* b2r = d_in[5];

    int N = in_sizes[0] / 128;
    int E = in_sizes[1] / 2;
    int NB = (N + 255) >> 8;

    char* w = (char*)d_ws;
    size_t off = 0;
    int*   flags = (int*)(w + off);   off += 256;      // flags[0..1]; gctr at flags[16]
    int*   gctr  = flags + 16;
    int*   deg_i = (int*)(w + off);   off = alignup(off + (size_t)N * 4);
    int*   row_start = (int*)(w + off); off = alignup(off + (size_t)N * 4);
    float* dinv  = (float*)(w + off); off = alignup(off + (size_t)N * 4);
    float* bb1   = (float*)(w + off); off = alignup(off + 128 * 4);
    float* bb2   = (float*)(w + off); off = alignup(off + 16 * 4);
    unsigned short* Wf1 = (unsigned short*)(w + off); off = alignup(off + 16384 * 2);
    unsigned short* Wf2 = (unsigned short*)(w + off); off = alignup(off + 2048 * 2);
    int*   bin_cnt = (int*)(w + off); off = alignup(off + (size_t)NB * 4);
    int*   adj   = (int*)(w + off);   off = alignup(off + (size_t)E * 4);
    unsigned short* h1t = (unsigned short*)(w + off); off = alignup(off + (size_t)N * 128 * 2);
    unsigned short* h2t = (unsigned short*)(w + off); off = alignup(off + (size_t)N * 16 * 2);
    int*   bin   = (int*)(w + off);   off = alignup(off + (size_t)NB * BCAP * 4);

    int gG = (N + 63) / 64;            // total gemm1 blocks
    int g1a = gG / 2;                  // first half -> front1
    int g1b = gG - g1a;                // second half -> front2 (overlaps binB)
    int gA = (E + 4095) / 4096;
    int gW = (N + 15) / 16;            // block-level 16-node tile, 4 waves x 4 nodes
    int gP = (N + 127) / 128;

    k_setup<<<12, 256, 0, stream>>>(W1r, W2r, b1r, b2r, (const unsigned int*)ei,
                                    Wf1, Wf2, bb1, bb2, bin_cnt, gctr, flags, NB);
    k_front1<<<gA + g1a, 256, 0, stream>>>(ei, bin_cnt, bin, E, NB, flags,
                                           xr, Wf1, h1t, N, gA);
    k_front2<<<NB + g1b, 256, 0, stream>>>(bin_cnt, bin, deg_i, row_start, dinv,
                                           adj, gctr, N, xr, Wf1, h1t, flags,
                                           NB, g1a);
    k_gather128<<<gW, 256, 0, stream>>>(h1t, row_start, deg_i, dinv, bb1, adj, Wf2, h2t, N);
    k_gather16<<<gP, 256, 0, stream>>>(h2t, row_start, deg_i, dinv, bb2, adj, d_out, N, flags);
}